// Round 8
// baseline (200.775 us; speedup 1.0000x reference)
//
#include <hip/hip_runtime.h>
#include <stdint.h>

typedef unsigned short u16;
typedef unsigned int u32;
typedef __bf16 bf16x8 __attribute__((ext_vector_type(8)));
typedef float f32x4 __attribute__((ext_vector_type(4)));

// ---------- helpers ----------
__device__ __forceinline__ float bf2f(u16 u) {
  return __builtin_bit_cast(float, (u32)u << 16);
}
__device__ __forceinline__ u16 f2b(float f) {
  u32 u = __builtin_bit_cast(u32, f);
  u32 r = (u + 0x7fffu + ((u >> 16) & 1u)) >> 16;  // RNE
  return (u16)r;
}
__device__ __forceinline__ void gload16(const u16* g, u16* l) {
  __builtin_amdgcn_global_load_lds(
      (const __attribute__((address_space(1))) u32*)(const void*)g,
      (__attribute__((address_space(3))) u32*)(void*)l, 16, 0, 0);
}
__device__ __forceinline__ void unpack16(uint4 a, uint4 b, float* o) {
  u32 w[8] = {a.x, a.y, a.z, a.w, b.x, b.y, b.z, b.w};
#pragma unroll
  for (int i = 0; i < 8; ++i) {
    o[2 * i]     = __builtin_bit_cast(float, w[i] << 16);
    o[2 * i + 1] = __builtin_bit_cast(float, w[i] & 0xffff0000u);
  }
}

// ---------- fp32 -> bf16 convert ----------
__global__ __launch_bounds__(256) void cvt_bf16(const float* __restrict__ in,
                                                u16* __restrict__ out, int n4) {
  int i = blockIdx.x * 256 + threadIdx.x;
  if (i >= n4) return;
  float4 v = reinterpret_cast<const float4*>(in)[i];
  ushort4 o;
  o.x = f2b(v.x); o.y = f2b(v.y); o.z = f2b(v.z); o.w = f2b(v.w);
  reinterpret_cast<ushort4*>(out)[i] = o;
}

// ---------- bf16 GEMM  C[M,N] = A[M,K] * B[N,K]^T ----------
// 256x128 tile, BK=32, 4 waves (2Mx2N), wave tile 128x64 (LDS intensity
// 42.7 FLOP/B vs 32 for 64x64 — the 128^2 family is LDS-BW-bound).
// Double-buffered LDS (48 KiB), ONE __syncthreads per K-tile:
//   { stage(t+1)->buf[nxt]; ds_read frags(t); 32 MFMA; sync }
// Sync's implicit vmcnt(0) drains loads issued a full tile earlier;
// overwrite of buf[t-1] is safe (its reads drained at sync of t-1).
// LDS swizzle (r5-measured zero-conflict): 16B-slot s -> s ^ ((row>>1)&3),
// pre-swizzled global source (linear global_load_lds dest) + same XOR on
// ds_read. 2 blocks/CU (VGPR<=256, LDS 96KiB).
// Grids: 768 (gemm1) / 512 (gemm2) = exactly 3.0 / 2.0 rounds on 256 CUs.
// MODE 0: bf16 out + fused per-head LN. MODE 1: fp32 out + bias.
template <int MODE>
__global__ __launch_bounds__(256, 2) void gemm_bt(
    const u16* __restrict__ A, const u16* __restrict__ B, void* __restrict__ C,
    const float* __restrict__ gq, const float* __restrict__ bq,
    const float* __restrict__ gk, const float* __restrict__ bk,
    const float* __restrict__ bias, int M, int N, int K, int ntn) {
  __shared__ u16 As[2][256 * 32];  // 32 KiB
  __shared__ u16 Bs[2][128 * 32];  // 16 KiB

  // XCD-aware bijective swizzle (grid % 8 == 0 at both call sites)
  const int nwg = gridDim.x;
  const int bid0 = blockIdx.x;
  const int bid = (bid0 & 7) * (nwg >> 3) + (bid0 >> 3);
  const int tm = bid / ntn, tn = bid % ntn;
  const int brow = tm << 8, bcol = tn << 7;
  const int tid = threadIdx.x;
  const int w = tid >> 6, lane = tid & 63;
  const int R0 = (w >> 1) << 7;  // wave row base: 0 / 128
  const int C0 = (w & 1) << 6;   // wave col base: 0 / 64
  const int lr = lane & 15, lg = lane >> 4;

  // staging: lane covers (row_in_group = lane>>2, slot = lane&3); global
  // source slot pre-swizzled: (lane&3) ^ ((row>>1)&3), row>>1 bits = lane>>3.
  const int sslot = (lane & 3) ^ ((lane >> 3) & 3);
  const u16* Asrc = A + (size_t)(brow + (lane >> 2)) * K + sslot * 8;
  const u16* Bsrc = B + (size_t)(bcol + (lane >> 2)) * K + sslot * 8;

  auto stage = [&](int t, int buf) {
    const int k0 = t << 5;
#pragma unroll
    for (int i = 0; i < 4; ++i) {  // A: 16 groups of 16 rows
      int g = w + 4 * i;
      gload16(Asrc + (size_t)(16 * g) * K + k0, &As[buf][(16 * g) * 32]);
    }
#pragma unroll
    for (int i = 0; i < 2; ++i) {  // B: 8 groups of 16 rows
      int g = w + 4 * i;
      gload16(Bsrc + (size_t)(16 * g) * K + k0, &Bs[buf][(16 * g) * 32]);
    }
  };

  f32x4 acc[8][4];
#pragma unroll
  for (int m = 0; m < 8; ++m)
#pragma unroll
    for (int n = 0; n < 4; ++n) acc[m][n] = (f32x4){0.f, 0.f, 0.f, 0.f};

  const int NC = K >> 5;
  // swizzled ds_read 16B-slot (elems): lg ^ ((row>>1)&3), row>>1 bits = lr>>1
  const int kslot = (lg ^ ((lr >> 1) & 3)) << 3;

  stage(0, 0);
  __syncthreads();

  for (int t = 0; t < NC; ++t) {
    const int cur = t & 1;
    if (t + 1 < NC) stage(t + 1, cur ^ 1);

    const u16* Asb = As[cur];
    const u16* Bsb = Bs[cur];
    bf16x8 af[8], bfr[4];
#pragma unroll
    for (int m = 0; m < 8; ++m)
      af[m] = *reinterpret_cast<const bf16x8*>(&Asb[(R0 + m * 16 + lr) * 32 + kslot]);
#pragma unroll
    for (int n = 0; n < 4; ++n)
      bfr[n] = *reinterpret_cast<const bf16x8*>(&Bsb[(C0 + n * 16 + lr) * 32 + kslot]);
    __builtin_amdgcn_s_setprio(1);
#pragma unroll
    for (int m = 0; m < 8; ++m)
#pragma unroll
      for (int n = 0; n < 4; ++n)
        acc[m][n] = __builtin_amdgcn_mfma_f32_16x16x32_bf16(af[m], bfr[n], acc[m][n], 0, 0, 0);
    __builtin_amdgcn_s_setprio(0);
    __syncthreads();  // implicit vmcnt(0): drains stage(t+1), full-tile cover
  }

  // C/D layout: col = lane&15, row = (lane>>4)*4 + reg
  const int orow = brow + R0 + (lg << 2);
  const int ocol = bcol + C0 + lr;
  if (MODE == 0) {
    const int wcol0 = bcol + C0;  // 64-aligned -> exactly one head slice
    const int sect = wcol0 >> 6;  // 0..7 q, 8..15 k, 16..23 v
    const bool doln = sect < 16;
    const float* Gp = (sect < 8) ? (gq + wcol0) : (gk + (wcol0 - 512));
    const float* Pp = (sect < 8) ? (bq + wcol0) : (bk + (wcol0 - 512));
    float gv[4], pv[4];
    if (doln) {
#pragma unroll
      for (int n = 0; n < 4; ++n) { gv[n] = Gp[n * 16 + lr]; pv[n] = Pp[n * 16 + lr]; }
    }
    u16* Cp = (u16*)C;
#pragma unroll
    for (int m = 0; m < 8; ++m)
#pragma unroll
      for (int r = 0; r < 4; ++r) {
        size_t rowoff = (size_t)(orow + m * 16 + r) * N;
        if (doln) {
          float s = 0.f, s2 = 0.f;
#pragma unroll
          for (int n = 0; n < 4; ++n) {
            float x = acc[m][n][r];
            s += x; s2 += x * x;
          }
#pragma unroll
          for (int off = 8; off; off >>= 1) {
            s += __shfl_xor(s, off, 64);
            s2 += __shfl_xor(s2, off, 64);
          }
          float mean = s * 0.015625f;
          float inv = rsqrtf(s2 * 0.015625f - mean * mean + 1e-5f);
#pragma unroll
          for (int n = 0; n < 4; ++n)
            Cp[rowoff + ocol + n * 16] =
                f2b((acc[m][n][r] - mean) * inv * gv[n] + pv[n]);
        } else {
#pragma unroll
          for (int n = 0; n < 4; ++n)
            Cp[rowoff + ocol + n * 16] = f2b(acc[m][n][r]);
        }
      }
  } else {
    float bvv[4];
#pragma unroll
    for (int n = 0; n < 4; ++n) bvv[n] = bias[ocol + n * 16];
    float* Cp = (float*)C;
#pragma unroll
    for (int m = 0; m < 8; ++m)
#pragma unroll
      for (int r = 0; r < 4; ++r) {
        size_t rowoff = (size_t)(orow + m * 16 + r) * N;
#pragma unroll
        for (int n = 0; n < 4; ++n)
          Cp[rowoff + ocol + n * 16] = acc[m][n][r] + bvv[n];
      }
  }
}

// ---------- KV[b,h,d,e] += sum_n k[n,d]*v[n,e]  (atomic partials over n-chunks) ----------
__global__ __launch_bounds__(256) void kv_accum(const u16* __restrict__ qkv,
                                                float* __restrict__ KV) {
  int nch = blockIdx.x & 7;   // 8 chunks of 512 rows
  int bh = blockIdx.x >> 3;   // 0..31
  int b = bh >> 3, h = bh & 7;
  __shared__ float ks[64][64];
  __shared__ float vs[64][64];
  int tid = threadIdx.x;
  int ty = tid >> 4, tx = tid & 15;
  int rr = tid >> 2, cc = (tid & 3) * 16;
  float acc[4][4];
#pragma unroll
  for (int i = 0; i < 4; ++i)
#pragma unroll
    for (int j = 0; j < 4; ++j) acc[i][j] = 0.f;

  for (int t = 0; t < 8; ++t) {
    int n0 = nch * 512 + t * 64;
    __syncthreads();
    size_t base = ((size_t)(b * 4096 + n0 + rr)) * 1536 + h * 64 + cc;
    const uint4* kp = reinterpret_cast<const uint4*>(&qkv[base + 512]);
    const uint4* vp = reinterpret_cast<const uint4*>(&qkv[base + 1024]);
    uint4 k0 = kp[0], k1 = kp[1];
    uint4 v0 = vp[0], v1 = vp[1];
    unpack16(k0, k1, &ks[rr][cc]);
    unpack16(v0, v1, &vs[rr][cc]);
    __syncthreads();
    for (int n = 0; n < 64; ++n) {
      float4 k4 = *reinterpret_cast<const float4*>(&ks[n][ty * 4]);
      float4 v4 = *reinterpret_cast<const float4*>(&vs[n][tx * 4]);
      float ka[4] = {k4.x, k4.y, k4.z, k4.w};
      float va[4] = {v4.x, v4.y, v4.z, v4.w};
#pragma unroll
      for (int i = 0; i < 4; ++i)
#pragma unroll
        for (int j = 0; j < 4; ++j) acc[i][j] += ka[i] * va[j];
    }
  }
  float* dst = KV + (size_t)bh * 4096;
#pragma unroll
  for (int i = 0; i < 4; ++i)
#pragma unroll
    for (int j = 0; j < 4; ++j)
      atomicAdd(&dst[(ty * 4 + i) * 64 + tx * 4 + j], acc[i][j]);
}

// ---------- attn[n, h*64+e] = scale * sum_d qn[n,d] * KV[b,h,d,e] ----------
__global__ __launch_bounds__(256) void attn_kernel(const u16* __restrict__ qkv,
                                                   const float* __restrict__ KV,
                                                   u16* __restrict__ attn) {
  int rblk = blockIdx.x;  // 64 rows per block, 256 blocks
  int b = rblk >> 6;
  __shared__ float qs[64][65];
  __shared__ float kvs[64][64];
  int tid = threadIdx.x;
  int ty = tid >> 4, tx = tid & 15;
  int rr = tid >> 2, cc = (tid & 3) * 16;
  const float scale = 1.0f / 32768.0f;  // 1/(sqrt(64)*4096)
  for (int h = 0; h < 8; ++h) {
    __syncthreads();
    size_t qbase = ((size_t)(rblk * 64 + rr)) * 1536 + h * 64 + cc;
    const uint4* qp = reinterpret_cast<const uint4*>(&qkv[qbase]);
    uint4 q0 = qp[0], q1 = qp[1];
    unpack16(q0, q1, &qs[rr][cc]);
    const float4* kp =
        reinterpret_cast<const float4*>(&KV[((size_t)(b * 8 + h)) * 4096 + rr * 64 + cc]);
#pragma unroll
    for (int j = 0; j < 4; ++j) {
      float4 t = kp[j];
      kvs[rr][cc + 4 * j + 0] = t.x;
      kvs[rr][cc + 4 * j + 1] = t.y;
      kvs[rr][cc + 4 * j + 2] = t.z;
      kvs[rr][cc + 4 * j + 3] = t.w;
    }
    __syncthreads();
    float acc[4][4] = {};
    for (int d = 0; d < 64; ++d) {
      float a0 = qs[ty * 4 + 0][d], a1 = qs[ty * 4 + 1][d];
      float a2 = qs[ty * 4 + 2][d], a3 = qs[ty * 4 + 3][d];
      float4 bv = *reinterpret_cast<const float4*>(&kvs[d][tx * 4]);
      float ba[4] = {bv.x, bv.y, bv.z, bv.w};
#pragma unroll
      for (int j = 0; j < 4; ++j) {
        acc[0][j] += a0 * ba[j];
        acc[1][j] += a1 * ba[j];
        acc[2][j] += a2 * ba[j];
        acc[3][j] += a3 * ba[j];
      }
    }
#pragma unroll
    for (int i = 0; i < 4; ++i) {
      int row = rblk * 64 + ty * 4 + i;
      ushort4 o;
      o.x = f2b(acc[i][0] * scale);
      o.y = f2b(acc[i][1] * scale);
      o.z = f2b(acc[i][2] * scale);
      o.w = f2b(acc[i][3] * scale);
      *reinterpret_cast<ushort4*>(&attn[(size_t)row * 512 + h * 64 + tx * 4]) = o;
    }
  }
}

// ---------- launch ----------
extern "C" void kernel_launch(void* const* d_in, const int* in_sizes, int n_in,
                              void* d_out, int out_size, void* d_ws, size_t ws_size,
                              hipStream_t stream) {
  const float* x  = (const float*)d_in[0];
  const float* Wq = (const float*)d_in[1];
  const float* gq = (const float*)d_in[2];
  const float* bq = (const float*)d_in[3];
  const float* gk = (const float*)d_in[4];
  const float* bk = (const float*)d_in[5];
  const float* Wo = (const float*)d_in[6];
  const float* bo = (const float*)d_in[7];
  float* out = (float*)d_out;

  char* p = (char*)d_ws;
  auto carve = [&](size_t bytes) {
    char* r = p;
    p += (bytes + 255) & ~(size_t)255;
    return r;
  };
  u16* xb    = (u16*)carve((size_t)16384 * 1024 * 2);
  u16* wqb   = (u16*)carve((size_t)1536 * 1024 * 2);
  u16* wob   = (u16*)carve((size_t)1024 * 512 * 2);
  u16* qkv   = (u16*)carve((size_t)16384 * 1536 * 2);
  float* KVb = (float*)carve((size_t)32 * 64 * 64 * 4);
  u16* attn  = (u16*)carve((size_t)16384 * 512 * 2);

  hipMemsetAsync(KVb, 0, (size_t)32 * 64 * 64 * 4, stream);
  cvt_bf16<<<16384, 256, 0, stream>>>(x, xb, 4194304);
  cvt_bf16<<<1536, 256, 0, stream>>>(Wq, wqb, 393216);
  cvt_bf16<<<512, 256, 0, stream>>>(Wo, wob, 131072);
  // qkv = x @ Wqkv^T  [16384,1536], fused per-head LN on q,k
  gemm_bt<0><<<64 * 12, 256, 0, stream>>>(xb, wqb, qkv, gq, bq, gk, bk, nullptr,
                                          16384, 1536, 1024, 12);
  // KV = k^T v per (b,h)
  kv_accum<<<256, 256, 0, stream>>>(qkv, KVb);
  // attn = scale * q @ KV
  attn_kernel<<<256, 256, 0, stream>>>(qkv, KVb, attn);
  // out = attn @ Wout^T + b_out  [16384,1024] fp32
  gemm_bt<1><<<64 * 8, 256, 0, stream>>>(attn, wob, out, nullptr, nullptr, nullptr,
                                         nullptr, bo, 16384, 1024, 512, 8);
}

// Round 9
// 189.227 us; speedup vs baseline: 1.0610x; 1.0610x over previous
//
#include <hip/hip_runtime.h>
#include <stdint.h>

typedef unsigned short u16;
typedef unsigned int u32;
typedef __bf16 bf16x8 __attribute__((ext_vector_type(8)));
typedef float f32x4 __attribute__((ext_vector_type(4)));

// ---------- helpers ----------
__device__ __forceinline__ float bf2f(u16 u) {
  return __builtin_bit_cast(float, (u32)u << 16);
}
__device__ __forceinline__ u16 f2b(float f) {
  u32 u = __builtin_bit_cast(u32, f);
  u32 r = (u + 0x7fffu + ((u >> 16) & 1u)) >> 16;  // RNE
  return (u16)r;
}
__device__ __forceinline__ void gload16(const u16* g, u16* l) {
  __builtin_amdgcn_global_load_lds(
      (const __attribute__((address_space(1))) u32*)(const void*)g,
      (__attribute__((address_space(3))) u32*)(void*)l, 16, 0, 0);
}
__device__ __forceinline__ void unpack16(uint4 a, uint4 b, float* o) {
  u32 w[8] = {a.x, a.y, a.z, a.w, b.x, b.y, b.z, b.w};
#pragma unroll
  for (int i = 0; i < 8; ++i) {
    o[2 * i]     = __builtin_bit_cast(float, w[i] << 16);
    o[2 * i + 1] = __builtin_bit_cast(float, w[i] & 0xffff0000u);
  }
}

// ---------- fp32 -> bf16 convert ----------
__global__ __launch_bounds__(256) void cvt_bf16(const float* __restrict__ in,
                                                u16* __restrict__ out, int n4) {
  int i = blockIdx.x * 256 + threadIdx.x;
  if (i >= n4) return;
  float4 v = reinterpret_cast<const float4*>(in)[i];
  ushort4 o;
  o.x = f2b(v.x); o.y = f2b(v.y); o.z = f2b(v.z); o.w = f2b(v.w);
  reinterpret_cast<ushort4*>(out)[i] = o;
}

// ---------- bf16 GEMM  C[M,N] = A[M,K] * B[N,K]^T ----------
// 128x128 tile, BK=32, 4 waves (2x2), 16x16x32 MFMA, double-buffered LDS.
// One __syncthreads per K-tile: {stage(t+1)->buf[nxt]; ds_read frags(t);
// 16 MFMA; sync}. The sync's implicit vmcnt(0) drains loads issued a full
// tile earlier (covered by reads+MFMA). Stage overwrite of buf[t-1] is safe:
// its reads completed before the end-of-(t-1) sync.
// LDS swizzle (r5/r8-measured ZERO-conflict): 16B-slot s -> s ^ ((row>>1)&3)
// — rows 0..7 cover all 32 banks exactly once; the 2-way lane8-15 alias is
// free. Pre-swizzled global source (linear global_load_lds dest) + same XOR
// on ds_read. (r7's s^(row&3) measured 6.3M conflicts: rows {0,4} collide.)
// MODE 0: bf16 out + fused per-head LN. MODE 1: fp32 out + bias.
template <int MODE>
__global__ __launch_bounds__(256, 3) void gemm_bt(
    const u16* __restrict__ A, const u16* __restrict__ B, void* __restrict__ C,
    const float* __restrict__ gq, const float* __restrict__ bq,
    const float* __restrict__ gk, const float* __restrict__ bk,
    const float* __restrict__ bias, int M, int N, int K, int ntn) {
  __shared__ u16 As[2][128 * 32];
  __shared__ u16 Bs[2][128 * 32];

  // XCD-aware bijective swizzle (grid % 8 == 0 at both call sites)
  const int nwg = gridDim.x;
  const int bid0 = blockIdx.x;
  const int bid = (bid0 & 7) * (nwg >> 3) + (bid0 >> 3);
  const int tm = bid / ntn, tn = bid % ntn;
  const int brow = tm << 7, bcol = tn << 7;
  const int tid = threadIdx.x;
  const int w = tid >> 6, lane = tid & 63;
  const int wrow = (w >> 1) << 6, wcol = (w & 1) << 6;
  const int lr = lane & 15, lg = lane >> 4;

  // staging: lane covers (row = 16g + lane/4, slot = lane&3); global source
  // slot pre-swizzled: (lane&3) ^ ((row>>1)&3), row>>1 bits = lane>>3.
  const int sslot = (lane & 3) ^ ((lane >> 3) & 3);
  const u16* Asrc = A + (size_t)(brow + (lane >> 2)) * K + sslot * 8;
  const u16* Bsrc = B + (size_t)(bcol + (lane >> 2)) * K + sslot * 8;

  auto stage = [&](int t, int buf) {
    const int k0 = t << 5;
#pragma unroll
    for (int i = 0; i < 2; ++i) {
      int g = w + 4 * i;  // wave-uniform row-group (16 rows, 1 KiB)
      gload16(Asrc + (size_t)(16 * g) * K + k0, &As[buf][(16 * g) * 32]);
      gload16(Bsrc + (size_t)(16 * g) * K + k0, &Bs[buf][(16 * g) * 32]);
    }
  };

  f32x4 acc[4][4];
#pragma unroll
  for (int m = 0; m < 4; ++m)
#pragma unroll
    for (int n = 0; n < 4; ++n) acc[m][n] = (f32x4){0.f, 0.f, 0.f, 0.f};

  const int NC = K >> 5;
  // swizzled ds_read 16B-slot (elems): lg ^ ((row>>1)&3), row>>1 bits = lr>>1
  const int kslot = (lg ^ ((lr >> 1) & 3)) << 3;

  stage(0, 0);
  __syncthreads();

  for (int t = 0; t < NC; ++t) {
    const int cur = t & 1;
    if (t + 1 < NC) stage(t + 1, cur ^ 1);

    const u16* Asb = As[cur];
    const u16* Bsb = Bs[cur];
    bf16x8 af[4], bfr[4];
#pragma unroll
    for (int m = 0; m < 4; ++m)
      af[m] = *reinterpret_cast<const bf16x8*>(&Asb[(wrow + m * 16 + lr) * 32 + kslot]);
#pragma unroll
    for (int n = 0; n < 4; ++n)
      bfr[n] = *reinterpret_cast<const bf16x8*>(&Bsb[(wcol + n * 16 + lr) * 32 + kslot]);
    __builtin_amdgcn_s_setprio(1);
#pragma unroll
    for (int m = 0; m < 4; ++m)
#pragma unroll
      for (int n = 0; n < 4; ++n)
        acc[m][n] = __builtin_amdgcn_mfma_f32_16x16x32_bf16(af[m], bfr[n], acc[m][n], 0, 0, 0);
    __builtin_amdgcn_s_setprio(0);
    __syncthreads();  // implicit vmcnt(0): drains stage(t+1), full-tile cover
  }

  // C/D layout: col = lane&15, row = (lane>>4)*4 + reg
  const int orow = brow + wrow + ((lane >> 4) << 2);
  const int ocol = bcol + wcol + lr;
  if (MODE == 0) {
    const int wcol0 = bcol + wcol;  // 64-aligned -> exactly one head slice
    const int sect = wcol0 >> 6;    // 0..7 q, 8..15 k, 16..23 v
    const bool doln = sect < 16;
    const float* Gp = (sect < 8) ? (gq + wcol0) : (gk + (wcol0 - 512));
    const float* Pp = (sect < 8) ? (bq + wcol0) : (bk + (wcol0 - 512));
    float gv[4], pv[4];
    if (doln) {
#pragma unroll
      for (int n = 0; n < 4; ++n) { gv[n] = Gp[n * 16 + lr]; pv[n] = Pp[n * 16 + lr]; }
    }
    u16* Cp = (u16*)C;
#pragma unroll
    for (int m = 0; m < 4; ++m)
#pragma unroll
      for (int r = 0; r < 4; ++r) {
        size_t rowoff = (size_t)(orow + m * 16 + r) * N;
        if (doln) {
          float s = 0.f, s2 = 0.f;
#pragma unroll
          for (int n = 0; n < 4; ++n) {
            float x = acc[m][n][r];
            s += x; s2 += x * x;
          }
#pragma unroll
          for (int off = 8; off; off >>= 1) {
            s += __shfl_xor(s, off, 64);
            s2 += __shfl_xor(s2, off, 64);
          }
          float mean = s * 0.015625f;
          float inv = rsqrtf(s2 * 0.015625f - mean * mean + 1e-5f);
#pragma unroll
          for (int n = 0; n < 4; ++n)
            Cp[rowoff + ocol + n * 16] =
                f2b((acc[m][n][r] - mean) * inv * gv[n] + pv[n]);
        } else {
#pragma unroll
          for (int n = 0; n < 4; ++n)
            Cp[rowoff + ocol + n * 16] = f2b(acc[m][n][r]);
        }
      }
  } else {
    float bvv[4];
#pragma unroll
    for (int n = 0; n < 4; ++n) bvv[n] = bias[ocol + n * 16];
    float* Cp = (float*)C;
#pragma unroll
    for (int m = 0; m < 4; ++m)
#pragma unroll
      for (int r = 0; r < 4; ++r) {
        size_t rowoff = (size_t)(orow + m * 16 + r) * N;
#pragma unroll
        for (int n = 0; n < 4; ++n)
          Cp[rowoff + ocol + n * 16] = acc[m][n][r] + bvv[n];
      }
  }
}

// ---------- KV[b,h,d,e] += sum_n k[n,d]*v[n,e]  (atomic partials over n-chunks) ----------
__global__ __launch_bounds__(256) void kv_accum(const u16* __restrict__ qkv,
                                                float* __restrict__ KV) {
  int nch = blockIdx.x & 7;   // 8 chunks of 512 rows
  int bh = blockIdx.x >> 3;   // 0..31
  int b = bh >> 3, h = bh & 7;
  __shared__ float ks[64][64];
  __shared__ float vs[64][64];
  int tid = threadIdx.x;
  int ty = tid >> 4, tx = tid & 15;
  int rr = tid >> 2, cc = (tid & 3) * 16;
  float acc[4][4];
#pragma unroll
  for (int i = 0; i < 4; ++i)
#pragma unroll
    for (int j = 0; j < 4; ++j) acc[i][j] = 0.f;

  for (int t = 0; t < 8; ++t) {
    int n0 = nch * 512 + t * 64;
    __syncthreads();
    size_t base = ((size_t)(b * 4096 + n0 + rr)) * 1536 + h * 64 + cc;
    const uint4* kp = reinterpret_cast<const uint4*>(&qkv[base + 512]);
    const uint4* vp = reinterpret_cast<const uint4*>(&qkv[base + 1024]);
    uint4 k0 = kp[0], k1 = kp[1];
    uint4 v0 = vp[0], v1 = vp[1];
    unpack16(k0, k1, &ks[rr][cc]);
    unpack16(v0, v1, &vs[rr][cc]);
    __syncthreads();
    for (int n = 0; n < 64; ++n) {
      float4 k4 = *reinterpret_cast<const float4*>(&ks[n][ty * 4]);
      float4 v4 = *reinterpret_cast<const float4*>(&vs[n][tx * 4]);
      float ka[4] = {k4.x, k4.y, k4.z, k4.w};
      float va[4] = {v4.x, v4.y, v4.z, v4.w};
#pragma unroll
      for (int i = 0; i < 4; ++i)
#pragma unroll
        for (int j = 0; j < 4; ++j) acc[i][j] += ka[i] * va[j];
    }
  }
  float* dst = KV + (size_t)bh * 4096;
#pragma unroll
  for (int i = 0; i < 4; ++i)
#pragma unroll
    for (int j = 0; j < 4; ++j)
      atomicAdd(&dst[(ty * 4 + i) * 64 + tx * 4 + j], acc[i][j]);
}

// ---------- attn[n, h*64+e] = scale * sum_d qn[n,d] * KV[b,h,d,e] ----------
__global__ __launch_bounds__(256) void attn_kernel(const u16* __restrict__ qkv,
                                                   const float* __restrict__ KV,
                                                   u16* __restrict__ attn) {
  int rblk = blockIdx.x;  // 64 rows per block, 256 blocks
  int b = rblk >> 6;
  __shared__ float qs[64][65];
  __shared__ float kvs[64][64];
  int tid = threadIdx.x;
  int ty = tid >> 4, tx = tid & 15;
  int rr = tid >> 2, cc = (tid & 3) * 16;
  const float scale = 1.0f / 32768.0f;  // 1/(sqrt(64)*4096)
  for (int h = 0; h < 8; ++h) {
    __syncthreads();
    size_t qbase = ((size_t)(rblk * 64 + rr)) * 1536 + h * 64 + cc;
    const uint4* qp = reinterpret_cast<const uint4*>(&qkv[qbase]);
    uint4 q0 = qp[0], q1 = qp[1];
    unpack16(q0, q1, &qs[rr][cc]);
    const float4* kp =
        reinterpret_cast<const float4*>(&KV[((size_t)(b * 8 + h)) * 4096 + rr * 64 + cc]);
#pragma unroll
    for (int j = 0; j < 4; ++j) {
      float4 t = kp[j];
      kvs[rr][cc + 4 * j + 0] = t.x;
      kvs[rr][cc + 4 * j + 1] = t.y;
      kvs[rr][cc + 4 * j + 2] = t.z;
      kvs[rr][cc + 4 * j + 3] = t.w;
    }
    __syncthreads();
    float acc[4][4] = {};
    for (int d = 0; d < 64; ++d) {
      float a0 = qs[ty * 4 + 0][d], a1 = qs[ty * 4 + 1][d];
      float a2 = qs[ty * 4 + 2][d], a3 = qs[ty * 4 + 3][d];
      float4 bv = *reinterpret_cast<const float4*>(&kvs[d][tx * 4]);
      float ba[4] = {bv.x, bv.y, bv.z, bv.w};
#pragma unroll
      for (int j = 0; j < 4; ++j) {
        acc[0][j] += a0 * ba[j];
        acc[1][j] += a1 * ba[j];
        acc[2][j] += a2 * ba[j];
        acc[3][j] += a3 * ba[j];
      }
    }
#pragma unroll
    for (int i = 0; i < 4; ++i) {
      int row = rblk * 64 + ty * 4 + i;
      ushort4 o;
      o.x = f2b(acc[i][0] * scale);
      o.y = f2b(acc[i][1] * scale);
      o.z = f2b(acc[i][2] * scale);
      o.w = f2b(acc[i][3] * scale);
      *reinterpret_cast<ushort4*>(&attn[(size_t)row * 512 + h * 64 + tx * 4]) = o;
    }
  }
}

// ---------- launch ----------
extern "C" void kernel_launch(void* const* d_in, const int* in_sizes, int n_in,
                              void* d_out, int out_size, void* d_ws, size_t ws_size,
                              hipStream_t stream) {
  const float* x  = (const float*)d_in[0];
  const float* Wq = (const float*)d_in[1];
  const float* gq = (const float*)d_in[2];
  const float* bq = (const float*)d_in[3];
  const float* gk = (const float*)d_in[4];
  const float* bk = (const float*)d_in[5];
  const float* Wo = (const float*)d_in[6];
  const float* bo = (const float*)d_in[7];
  float* out = (float*)d_out;

  char* p = (char*)d_ws;
  auto carve = [&](size_t bytes) {
    char* r = p;
    p += (bytes + 255) & ~(size_t)255;
    return r;
  };
  u16* xb    = (u16*)carve((size_t)16384 * 1024 * 2);
  u16* wqb   = (u16*)carve((size_t)1536 * 1024 * 2);
  u16* wob   = (u16*)carve((size_t)1024 * 512 * 2);
  u16* qkv   = (u16*)carve((size_t)16384 * 1536 * 2);
  float* KVb = (float*)carve((size_t)32 * 64 * 64 * 4);
  u16* attn  = (u16*)carve((size_t)16384 * 512 * 2);

  hipMemsetAsync(KVb, 0, (size_t)32 * 64 * 64 * 4, stream);
  cvt_bf16<<<16384, 256, 0, stream>>>(x, xb, 4194304);
  cvt_bf16<<<1536, 256, 0, stream>>>(Wq, wqb, 393216);
  cvt_bf16<<<512, 256, 0, stream>>>(Wo, wob, 131072);
  // qkv = x @ Wqkv^T  [16384,1536], fused per-head LN on q,k
  gemm_bt<0><<<128 * 12, 256, 0, stream>>>(xb, wqb, qkv, gq, bq, gk, bk, nullptr,
                                           16384, 1536, 1024, 12);
  // KV = k^T v per (b,h)
  kv_accum<<<256, 256, 0, stream>>>(qkv, KVb);
  // attn = scale * q @ KV
  attn_kernel<<<256, 256, 0, stream>>>(qkv, KVb, attn);
  // out = attn @ Wout^T + b_out  [16384,1024] fp32
  gemm_bt<1><<<128 * 8, 256, 0, stream>>>(attn, wob, out, nullptr, nullptr, nullptr,
                                          nullptr, bo, 16384, 1024, 512, 8);
}

// Round 10
// 179.811 us; speedup vs baseline: 1.1166x; 1.0524x over previous
//
#include <hip/hip_runtime.h>
#include <stdint.h>

typedef unsigned short u16;
typedef unsigned int u32;
typedef __bf16 bf16x8 __attribute__((ext_vector_type(8)));
typedef float f32x4 __attribute__((ext_vector_type(4)));

// ---------- helpers ----------
__device__ __forceinline__ float bf2f(u16 u) {
  return __builtin_bit_cast(float, (u32)u << 16);
}
__device__ __forceinline__ u16 f2b(float f) {
  u32 u = __builtin_bit_cast(u32, f);
  u32 r = (u + 0x7fffu + ((u >> 16) & 1u)) >> 16;  // RNE
  return (u16)r;
}
__device__ __forceinline__ void gload16(const u16* g, u16* l) {
  __builtin_amdgcn_global_load_lds(
      (const __attribute__((address_space(1))) u32*)(const void*)g,
      (__attribute__((address_space(3))) u32*)(void*)l, 16, 0, 0);
}
__device__ __forceinline__ void unpack16(uint4 a, uint4 b, float* o) {
  u32 w[8] = {a.x, a.y, a.z, a.w, b.x, b.y, b.z, b.w};
#pragma unroll
  for (int i = 0; i < 8; ++i) {
    o[2 * i]     = __builtin_bit_cast(float, w[i] << 16);
    o[2 * i + 1] = __builtin_bit_cast(float, w[i] & 0xffff0000u);
  }
}

// ---------- fp32 -> bf16 convert ----------
__global__ __launch_bounds__(256) void cvt_bf16(const float* __restrict__ in,
                                                u16* __restrict__ out, int n4) {
  int i = blockIdx.x * 256 + threadIdx.x;
  if (i >= n4) return;
  float4 v = reinterpret_cast<const float4*>(in)[i];
  ushort4 o;
  o.x = f2b(v.x); o.y = f2b(v.y); o.z = f2b(v.z); o.w = f2b(v.w);
  reinterpret_cast<ushort4*>(out)[i] = o;
}

// ---------- bf16 GEMM  C[M,N] = A[M,K] * B[N,K]^T ----------
// 128x128 tile, BK=32, 4 waves (2x2), 16x16x32 MFMA, double-buffered LDS,
// one __syncthreads per K-tile (r9-verified structure, zero bank conflicts).
// A row stride = lda (lets gemm2 read the q-section of qkv in place).
// MODE 1: B is per-batch (W2[b]): Bp = B + (brow>>12)*bstride.
// MODE 0: bf16 out + fused per-head LN. MODE 1: fp32 out + bias.
template <int MODE>
__global__ __launch_bounds__(256, 4) void gemm_bt(
    const u16* __restrict__ A, const u16* __restrict__ B, void* __restrict__ C,
    const float* __restrict__ gq, const float* __restrict__ bq,
    const float* __restrict__ gk, const float* __restrict__ bk,
    const float* __restrict__ bias, int M, int N, int K, int ntn,
    int lda, size_t bstride) {
  __shared__ u16 As[2][128 * 32];
  __shared__ u16 Bs[2][128 * 32];

  // XCD-aware bijective swizzle (grid % 8 == 0 at both call sites)
  const int nwg = gridDim.x;
  const int bid0 = blockIdx.x;
  const int bid = (bid0 & 7) * (nwg >> 3) + (bid0 >> 3);
  const int tm = bid / ntn, tn = bid % ntn;
  const int brow = tm << 7, bcol = tn << 7;
  const int tid = threadIdx.x;
  const int w = tid >> 6, lane = tid & 63;
  const int wrow = (w >> 1) << 6, wcol = (w & 1) << 6;
  const int lr = lane & 15, lg = lane >> 4;

  const u16* Bp = (MODE == 1) ? (B + (size_t)(brow >> 12) * bstride) : B;

  // staging: lane covers (row = 16g + lane/4, slot = lane&3); global source
  // slot pre-swizzled: (lane&3) ^ ((row>>1)&3), row>>1 bits = lane>>3.
  const int sslot = (lane & 3) ^ ((lane >> 3) & 3);
  const u16* Asrc = A + (size_t)(brow + (lane >> 2)) * lda + sslot * 8;
  const u16* Bsrc = Bp + (size_t)(bcol + (lane >> 2)) * K + sslot * 8;

  auto stage = [&](int t, int buf) {
    const int k0 = t << 5;
#pragma unroll
    for (int i = 0; i < 2; ++i) {
      int g = w + 4 * i;  // wave-uniform row-group (16 rows, 1 KiB)
      gload16(Asrc + (size_t)(16 * g) * lda + k0, &As[buf][(16 * g) * 32]);
      gload16(Bsrc + (size_t)(16 * g) * K + k0, &Bs[buf][(16 * g) * 32]);
    }
  };

  f32x4 acc[4][4];
#pragma unroll
  for (int m = 0; m < 4; ++m)
#pragma unroll
    for (int n = 0; n < 4; ++n) acc[m][n] = (f32x4){0.f, 0.f, 0.f, 0.f};

  const int NC = K >> 5;
  // swizzled ds_read 16B-slot (elems): lg ^ ((row>>1)&3), row>>1 bits = lr>>1
  const int kslot = (lg ^ ((lr >> 1) & 3)) << 3;

  stage(0, 0);
  __syncthreads();

  for (int t = 0; t < NC; ++t) {
    const int cur = t & 1;
    if (t + 1 < NC) stage(t + 1, cur ^ 1);

    const u16* Asb = As[cur];
    const u16* Bsb = Bs[cur];
    bf16x8 af[4], bfr[4];
#pragma unroll
    for (int m = 0; m < 4; ++m)
      af[m] = *reinterpret_cast<const bf16x8*>(&Asb[(wrow + m * 16 + lr) * 32 + kslot]);
#pragma unroll
    for (int n = 0; n < 4; ++n)
      bfr[n] = *reinterpret_cast<const bf16x8*>(&Bsb[(wcol + n * 16 + lr) * 32 + kslot]);
    __builtin_amdgcn_s_setprio(1);
#pragma unroll
    for (int m = 0; m < 4; ++m)
#pragma unroll
      for (int n = 0; n < 4; ++n)
        acc[m][n] = __builtin_amdgcn_mfma_f32_16x16x32_bf16(af[m], bfr[n], acc[m][n], 0, 0, 0);
    __builtin_amdgcn_s_setprio(0);
    __syncthreads();  // implicit vmcnt(0): drains stage(t+1), full-tile cover
  }

  // C/D layout: col = lane&15, row = (lane>>4)*4 + reg
  const int orow = brow + wrow + ((lane >> 4) << 2);
  const int ocol = bcol + wcol + lr;
  if (MODE == 0) {
    const int wcol0 = bcol + wcol;  // 64-aligned -> exactly one head slice
    const int sect = wcol0 >> 6;    // 0..7 q, 8..15 k, 16..23 v
    const bool doln = sect < 16;
    const float* Gp = (sect < 8) ? (gq + wcol0) : (gk + (wcol0 - 512));
    const float* Pp = (sect < 8) ? (bq + wcol0) : (bk + (wcol0 - 512));
    float gv[4], pv[4];
    if (doln) {
#pragma unroll
      for (int n = 0; n < 4; ++n) { gv[n] = Gp[n * 16 + lr]; pv[n] = Pp[n * 16 + lr]; }
    }
    u16* Cp = (u16*)C;
#pragma unroll
    for (int m = 0; m < 4; ++m)
#pragma unroll
      for (int r = 0; r < 4; ++r) {
        size_t rowoff = (size_t)(orow + m * 16 + r) * N;
        if (doln) {
          float s = 0.f, s2 = 0.f;
#pragma unroll
          for (int n = 0; n < 4; ++n) {
            float x = acc[m][n][r];
            s += x; s2 += x * x;
          }
#pragma unroll
          for (int off = 8; off; off >>= 1) {
            s += __shfl_xor(s, off, 64);
            s2 += __shfl_xor(s2, off, 64);
          }
          float mean = s * 0.015625f;
          float inv = rsqrtf(s2 * 0.015625f - mean * mean + 1e-5f);
#pragma unroll
          for (int n = 0; n < 4; ++n)
            Cp[rowoff + ocol + n * 16] =
                f2b((acc[m][n][r] - mean) * inv * gv[n] + pv[n]);
        } else {
#pragma unroll
          for (int n = 0; n < 4; ++n)
            Cp[rowoff + ocol + n * 16] = f2b(acc[m][n][r]);
        }
      }
  } else {
    float bvv[4];
#pragma unroll
    for (int n = 0; n < 4; ++n) bvv[n] = bias[ocol + n * 16];
    float* Cp = (float*)C;
#pragma unroll
    for (int m = 0; m < 4; ++m)
#pragma unroll
      for (int r = 0; r < 4; ++r) {
        size_t rowoff = (size_t)(orow + m * 16 + r) * N;
#pragma unroll
        for (int n = 0; n < 4; ++n)
          Cp[rowoff + ocol + n * 16] = acc[m][n][r] + bvv[n];
      }
  }
}

// ---------- KV[b,h,d,e] += sum_n k[n,d]*v[n,e]  (atomic partials, 16 n-chunks) ----------
__global__ __launch_bounds__(256) void kv_accum(const u16* __restrict__ qkv,
                                                float* __restrict__ KV) {
  int nch = blockIdx.x & 15;  // 16 chunks of 256 rows
  int bh = blockIdx.x >> 4;   // 0..31
  int b = bh >> 3, h = bh & 7;
  __shared__ float ks[64][64];
  __shared__ float vs[64][64];
  int tid = threadIdx.x;
  int ty = tid >> 4, tx = tid & 15;
  int rr = tid >> 2, cc = (tid & 3) * 16;
  float acc[4][4];
#pragma unroll
  for (int i = 0; i < 4; ++i)
#pragma unroll
    for (int j = 0; j < 4; ++j) acc[i][j] = 0.f;

  for (int t = 0; t < 4; ++t) {
    int n0 = nch * 256 + t * 64;
    __syncthreads();
    size_t base = ((size_t)(b * 4096 + n0 + rr)) * 1536 + h * 64 + cc;
    const uint4* kp = reinterpret_cast<const uint4*>(&qkv[base + 512]);
    const uint4* vp = reinterpret_cast<const uint4*>(&qkv[base + 1024]);
    uint4 k0 = kp[0], k1 = kp[1];
    uint4 v0 = vp[0], v1 = vp[1];
    unpack16(k0, k1, &ks[rr][cc]);
    unpack16(v0, v1, &vs[rr][cc]);
    __syncthreads();
    for (int n = 0; n < 64; ++n) {
      float4 k4 = *reinterpret_cast<const float4*>(&ks[n][ty * 4]);
      float4 v4 = *reinterpret_cast<const float4*>(&vs[n][tx * 4]);
      float ka[4] = {k4.x, k4.y, k4.z, k4.w};
      float va[4] = {v4.x, v4.y, v4.z, v4.w};
#pragma unroll
      for (int i = 0; i < 4; ++i)
#pragma unroll
        for (int j = 0; j < 4; ++j) acc[i][j] += ka[i] * va[j];
    }
  }
  float* dst = KV + (size_t)bh * 4096;
#pragma unroll
  for (int i = 0; i < 4; ++i)
#pragma unroll
    for (int j = 0; j < 4; ++j)
      atomicAdd(&dst[(ty * 4 + i) * 64 + tx * 4 + j], acc[i][j]);
}

// ---------- W2[b][j][h*64+d] = scale * sum_e KV[b,h,d,e] * Wo[j,h*64+e] ----------
// Folds KV@Wo^T (and the 1/(sqrt(dh)*n) scale) into a tiny per-batch weight,
// eliminating the attn intermediate: out = q @ W2[b]^T + b_out.
__global__ __launch_bounds__(256) void w2_kernel(const float* __restrict__ KV,
                                                 const u16* __restrict__ wob,
                                                 u16* __restrict__ w2) {
  int bh = blockIdx.x & 31, jt = blockIdx.x >> 5;  // jt 0..7
  int b = bh >> 3, h = bh & 7;
  __shared__ float kvs[64][64];
  int t = threadIdx.x;
  {
    const float4* src = reinterpret_cast<const float4*>(KV + (size_t)bh * 4096);
    float4* dst = reinterpret_cast<float4*>(&kvs[0][0]);
#pragma unroll
    for (int i = 0; i < 4; ++i) dst[t + 256 * i] = src[t + 256 * i];
  }
  __syncthreads();
  int jloc = t & 127, dg = t >> 7;
  int j = jt * 128 + jloc;
  float wo[64];
  const u16* wr = wob + (size_t)j * 512 + h * 64;
#pragma unroll
  for (int e8 = 0; e8 < 8; ++e8) {
    uint4 pk = *reinterpret_cast<const uint4*>(wr + e8 * 8);
    u32 wds[4] = {pk.x, pk.y, pk.z, pk.w};
#pragma unroll
    for (int i = 0; i < 4; ++i) {
      wo[e8 * 8 + 2 * i]     = bf2f((u16)(wds[i] & 0xffffu));
      wo[e8 * 8 + 2 * i + 1] = bf2f((u16)(wds[i] >> 16));
    }
  }
  const float scale = 1.0f / 32768.0f;  // 1/(sqrt(64)*4096)
  u16* outp = w2 + ((size_t)b * 1024 + j) * 512 + h * 64 + dg * 32;
#pragma unroll
  for (int dd = 0; dd < 32; ++dd) {
    int d = dg * 32 + dd;
    float acc = 0.f;
    const float4* kr = reinterpret_cast<const float4*>(&kvs[d][0]);
#pragma unroll
    for (int e4 = 0; e4 < 16; ++e4) {
      float4 kv4 = kr[e4];
      acc += kv4.x * wo[e4 * 4] + kv4.y * wo[e4 * 4 + 1] +
             kv4.z * wo[e4 * 4 + 2] + kv4.w * wo[e4 * 4 + 3];
    }
    outp[dd] = f2b(acc * scale);
  }
}

// ---------- launch ----------
extern "C" void kernel_launch(void* const* d_in, const int* in_sizes, int n_in,
                              void* d_out, int out_size, void* d_ws, size_t ws_size,
                              hipStream_t stream) {
  const float* x  = (const float*)d_in[0];
  const float* Wq = (const float*)d_in[1];
  const float* gq = (const float*)d_in[2];
  const float* bq = (const float*)d_in[3];
  const float* gk = (const float*)d_in[4];
  const float* bk = (const float*)d_in[5];
  const float* Wo = (const float*)d_in[6];
  const float* bo = (const float*)d_in[7];
  float* out = (float*)d_out;

  char* p = (char*)d_ws;
  auto carve = [&](size_t bytes) {
    char* r = p;
    p += (bytes + 255) & ~(size_t)255;
    return r;
  };
  u16* xb    = (u16*)carve((size_t)16384 * 1024 * 2);
  u16* wqb   = (u16*)carve((size_t)1536 * 1024 * 2);
  u16* wob   = (u16*)carve((size_t)1024 * 512 * 2);
  u16* qkv   = (u16*)carve((size_t)16384 * 1536 * 2);
  float* KVb = (float*)carve((size_t)32 * 64 * 64 * 4);
  u16* w2b   = (u16*)carve((size_t)4 * 1024 * 512 * 2);

  hipMemsetAsync(KVb, 0, (size_t)32 * 64 * 64 * 4, stream);
  cvt_bf16<<<16384, 256, 0, stream>>>(x, xb, 4194304);
  cvt_bf16<<<1536, 256, 0, stream>>>(Wq, wqb, 393216);
  cvt_bf16<<<512, 256, 0, stream>>>(Wo, wob, 131072);
  // qkv = x @ Wqkv^T  [16384,1536], fused per-head LN on q,k
  gemm_bt<0><<<128 * 12, 256, 0, stream>>>(xb, wqb, qkv, gq, bq, gk, bk, nullptr,
                                           16384, 1536, 1024, 12, 1024, 0);
  // KV = k^T v per (b,h)
  kv_accum<<<512, 256, 0, stream>>>(qkv, KVb);
  // W2[b] = scale * KV[b] @ Wo-slices
  w2_kernel<<<256, 256, 0, stream>>>(KVb, wob, w2b);
  // out = q @ W2[b]^T + b_out  [16384,1024] fp32  (A = q section of qkv)
  gemm_bt<1><<<128 * 8, 256, 0, stream>>>(qkv, w2b, out, nullptr, nullptr, nullptr,
                                          nullptr, bo, 16384, 1024, 512, 8,
                                          1536, (size_t)1024 * 512);
}

// Round 11
// 176.754 us; speedup vs baseline: 1.1359x; 1.0173x over previous
//
#include <hip/hip_runtime.h>
#include <stdint.h>

typedef unsigned short u16;
typedef unsigned int u32;
typedef __bf16 bf16x8 __attribute__((ext_vector_type(8)));
typedef float f32x4 __attribute__((ext_vector_type(4)));

// ---------- helpers ----------
__device__ __forceinline__ float bf2f(u16 u) {
  return __builtin_bit_cast(float, (u32)u << 16);
}
__device__ __forceinline__ u16 f2b(float f) {
  u32 u = __builtin_bit_cast(u32, f);
  u32 r = (u + 0x7fffu + ((u >> 16) & 1u)) >> 16;  // RNE
  return (u16)r;
}
__device__ __forceinline__ void gload16(const u16* g, u16* l) {
  __builtin_amdgcn_global_load_lds(
      (const __attribute__((address_space(1))) u32*)(const void*)g,
      (__attribute__((address_space(3))) u32*)(void*)l, 16, 0, 0);
}
__device__ __forceinline__ void unpack16(uint4 a, uint4 b, float* o) {
  u32 w[8] = {a.x, a.y, a.z, a.w, b.x, b.y, b.z, b.w};
#pragma unroll
  for (int i = 0; i < 8; ++i) {
    o[2 * i]     = __builtin_bit_cast(float, w[i] << 16);
    o[2 * i + 1] = __builtin_bit_cast(float, w[i] & 0xffff0000u);
  }
}

// ---------- fp32 -> bf16 convert (weights only) ----------
__global__ __launch_bounds__(256) void cvt_bf16(const float* __restrict__ in,
                                                u16* __restrict__ out, int n4) {
  int i = blockIdx.x * 256 + threadIdx.x;
  if (i >= n4) return;
  float4 v = reinterpret_cast<const float4*>(in)[i];
  ushort4 o;
  o.x = f2b(v.x); o.y = f2b(v.y); o.z = f2b(v.z); o.w = f2b(v.w);
  reinterpret_cast<ushort4*>(out)[i] = o;
}

// ---------- bf16 GEMM  C[M,N] = A[M,K] * B[N,K]^T ----------
// 128x128 tile, BK=32, 4 waves (2x2), 16x16x32 MFMA, double-buffered LDS,
// one __syncthreads per K-tile (r9-verified structure, zero bank conflicts).
// AF32=1: A is fp32, reg-staged (T14 issue-early/write-late): float4 loads
//   issued at iter top (latency covered by ds_read+MFMA), converted to bf16
//   and ds_write'd to the swizzled slot after MFMA, before the sync. Fuses
//   the x->bf16 conversion into gemm1, eliminating the cvt_x round-trip.
// AF32=0: A bf16 via global_load_lds (pre-swizzled source, linear dest).
// LDS swizzle (r9-verified zero-conflict): 16B-slot s -> s ^ ((row>>1)&3).
// MODE 0: bf16 out + fused per-head LN. MODE 1: fp32 out + bias, B per-batch.
template <int MODE, int AF32>
__global__ __launch_bounds__(256, 4) void gemm_bt(
    const void* __restrict__ Av, const u16* __restrict__ B, void* __restrict__ C,
    const float* __restrict__ gq, const float* __restrict__ bq,
    const float* __restrict__ gk, const float* __restrict__ bk,
    const float* __restrict__ bias, int M, int N, int K, int ntn,
    int lda, size_t bstride) {
  __shared__ u16 As[2][128 * 32];
  __shared__ u16 Bs[2][128 * 32];

  // XCD-aware bijective swizzle (grid % 8 == 0 at both call sites)
  const int nwg = gridDim.x;
  const int bid0 = blockIdx.x;
  const int bid = (bid0 & 7) * (nwg >> 3) + (bid0 >> 3);
  const int tm = bid / ntn, tn = bid % ntn;
  const int brow = tm << 7, bcol = tn << 7;
  const int tid = threadIdx.x;
  const int w = tid >> 6, lane = tid & 63;
  const int wrow = (w >> 1) << 6, wcol = (w & 1) << 6;
  const int lr = lane & 15, lg = lane >> 4;

  const u16* Bp = (MODE == 1) ? (B + (size_t)(brow >> 12) * bstride) : B;

  // staging geometry: lane covers (row = 16g + lane>>2, 16B-slot = lane&3);
  // swizzled slot = (lane&3) ^ ((row>>1)&3), (row>>1)&3 == (lane>>3)&3.
  const int swslot = (lane & 3) ^ ((lane >> 3) & 3);
  const u16* Aus  = (const u16*)Av + (size_t)(brow + (lane >> 2)) * lda + swslot * 8;
  const float* Af = (const float*)Av + (size_t)(brow + (lane >> 2)) * lda + (lane & 3) * 8;
  const u16* Bsrc = Bp + (size_t)(bcol + (lane >> 2)) * K + swslot * 8;

  auto stageB = [&](int t, int buf) {
    const int k0 = t << 5;
#pragma unroll
    for (int i = 0; i < 2; ++i) {
      int g = w + 4 * i;  // wave-uniform row-group (16 rows, 1 KiB)
      gload16(Bsrc + (size_t)(16 * g) * K + k0, &Bs[buf][(16 * g) * 32]);
    }
  };
  auto stageA16 = [&](int t, int buf) {
    const int k0 = t << 5;
#pragma unroll
    for (int i = 0; i < 2; ++i) {
      int g = w + 4 * i;
      gload16(Aus + (size_t)(16 * g) * lda + k0, &As[buf][(16 * g) * 32]);
    }
  };

  float4 pa[2][2];  // in-flight fp32 A (AF32 path)
  auto issueA = [&](int t) {
    const int k0 = t << 5;
#pragma unroll
    for (int i = 0; i < 2; ++i) {
      int g = w + 4 * i;
      const float4* s = reinterpret_cast<const float4*>(Af + (size_t)(16 * g) * lda + k0);
      pa[i][0] = s[0];
      pa[i][1] = s[1];
    }
  };
  auto writeA = [&](int buf) {
#pragma unroll
    for (int i = 0; i < 2; ++i) {
      int g = w + 4 * i;
      bf16x8 vv;
      vv[0] = (__bf16)pa[i][0].x; vv[1] = (__bf16)pa[i][0].y;
      vv[2] = (__bf16)pa[i][0].z; vv[3] = (__bf16)pa[i][0].w;
      vv[4] = (__bf16)pa[i][1].x; vv[5] = (__bf16)pa[i][1].y;
      vv[6] = (__bf16)pa[i][1].z; vv[7] = (__bf16)pa[i][1].w;
      *reinterpret_cast<bf16x8*>(
          &As[buf][(16 * g + (lane >> 2)) * 32 + (swslot << 3)]) = vv;
    }
  };

  f32x4 acc[4][4];
#pragma unroll
  for (int m = 0; m < 4; ++m)
#pragma unroll
    for (int n = 0; n < 4; ++n) acc[m][n] = (f32x4){0.f, 0.f, 0.f, 0.f};

  const int NC = K >> 5;
  // swizzled ds_read 16B-slot (elems): lg ^ ((row>>1)&3), row>>1 bits = lr>>1
  const int kslot = (lg ^ ((lr >> 1) & 3)) << 3;

  // prologue: tile 0
  if (AF32) {
    issueA(0);
    stageB(0, 0);
    writeA(0);
  } else {
    stageA16(0, 0);
    stageB(0, 0);
  }
  __syncthreads();

  for (int t = 0; t < NC; ++t) {
    const int cur = t & 1;
    if (t + 1 < NC) {
      stageB(t + 1, cur ^ 1);
      if (AF32) issueA(t + 1); else stageA16(t + 1, cur ^ 1);
    }

    const u16* Asb = As[cur];
    const u16* Bsb = Bs[cur];
    bf16x8 af[4], bfr[4];
#pragma unroll
    for (int m = 0; m < 4; ++m)
      af[m] = *reinterpret_cast<const bf16x8*>(&Asb[(wrow + m * 16 + lr) * 32 + kslot]);
#pragma unroll
    for (int n = 0; n < 4; ++n)
      bfr[n] = *reinterpret_cast<const bf16x8*>(&Bsb[(wcol + n * 16 + lr) * 32 + kslot]);
    __builtin_amdgcn_s_setprio(1);
#pragma unroll
    for (int m = 0; m < 4; ++m)
#pragma unroll
      for (int n = 0; n < 4; ++n)
        acc[m][n] = __builtin_amdgcn_mfma_f32_16x16x32_bf16(af[m], bfr[n], acc[m][n], 0, 0, 0);
    __builtin_amdgcn_s_setprio(0);
    if (AF32 && t + 1 < NC) writeA(cur ^ 1);  // fp32 loads waited here, post-MFMA
    __syncthreads();  // drains vmcnt (B gload, A loads) + lgkm (A writes)
  }

  // C/D layout: col = lane&15, row = (lane>>4)*4 + reg
  const int orow = brow + wrow + ((lane >> 4) << 2);
  const int ocol = bcol + wcol + lr;
  if (MODE == 0) {
    const int wcol0 = bcol + wcol;  // 64-aligned -> exactly one head slice
    const int sect = wcol0 >> 6;    // 0..7 q, 8..15 k, 16..23 v
    const bool doln = sect < 16;
    const float* Gp = (sect < 8) ? (gq + wcol0) : (gk + (wcol0 - 512));
    const float* Pp = (sect < 8) ? (bq + wcol0) : (bk + (wcol0 - 512));
    float gv[4], pv[4];
    if (doln) {
#pragma unroll
      for (int n = 0; n < 4; ++n) { gv[n] = Gp[n * 16 + lr]; pv[n] = Pp[n * 16 + lr]; }
    }
    u16* Cp = (u16*)C;
#pragma unroll
    for (int m = 0; m < 4; ++m)
#pragma unroll
      for (int r = 0; r < 4; ++r) {
        size_t rowoff = (size_t)(orow + m * 16 + r) * N;
        if (doln) {
          float s = 0.f, s2 = 0.f;
#pragma unroll
          for (int n = 0; n < 4; ++n) {
            float x = acc[m][n][r];
            s += x; s2 += x * x;
          }
#pragma unroll
          for (int off = 8; off; off >>= 1) {
            s += __shfl_xor(s, off, 64);
            s2 += __shfl_xor(s2, off, 64);
          }
          float mean = s * 0.015625f;
          float inv = rsqrtf(s2 * 0.015625f - mean * mean + 1e-5f);
#pragma unroll
          for (int n = 0; n < 4; ++n)
            Cp[rowoff + ocol + n * 16] =
                f2b((acc[m][n][r] - mean) * inv * gv[n] + pv[n]);
        } else {
#pragma unroll
          for (int n = 0; n < 4; ++n)
            Cp[rowoff + ocol + n * 16] = f2b(acc[m][n][r]);
        }
      }
  } else {
    float bvv[4];
#pragma unroll
    for (int n = 0; n < 4; ++n) bvv[n] = bias[ocol + n * 16];
    float* Cp = (float*)C;
#pragma unroll
    for (int m = 0; m < 4; ++m)
#pragma unroll
      for (int r = 0; r < 4; ++r) {
        size_t rowoff = (size_t)(orow + m * 16 + r) * N;
#pragma unroll
        for (int n = 0; n < 4; ++n)
          Cp[rowoff + ocol + n * 16] = acc[m][n][r] + bvv[n];
      }
  }
}

// ---------- KV[b,h,d,e] += sum_n k[n,d]*v[n,e]  (atomic partials, 16 n-chunks) ----------
__global__ __launch_bounds__(256) void kv_accum(const u16* __restrict__ qkv,
                                                float* __restrict__ KV) {
  int nch = blockIdx.x & 15;  // 16 chunks of 256 rows
  int bh = blockIdx.x >> 4;   // 0..31
  int b = bh >> 3, h = bh & 7;
  __shared__ float ks[64][64];
  __shared__ float vs[64][64];
  int tid = threadIdx.x;
  int ty = tid >> 4, tx = tid & 15;
  int rr = tid >> 2, cc = (tid & 3) * 16;
  float acc[4][4];
#pragma unroll
  for (int i = 0; i < 4; ++i)
#pragma unroll
    for (int j = 0; j < 4; ++j) acc[i][j] = 0.f;

  for (int t = 0; t < 4; ++t) {
    int n0 = nch * 256 + t * 64;
    __syncthreads();
    size_t base = ((size_t)(b * 4096 + n0 + rr)) * 1536 + h * 64 + cc;
    const uint4* kp = reinterpret_cast<const uint4*>(&qkv[base + 512]);
    const uint4* vp = reinterpret_cast<const uint4*>(&qkv[base + 1024]);
    uint4 k0 = kp[0], k1 = kp[1];
    uint4 v0 = vp[0], v1 = vp[1];
    unpack16(k0, k1, &ks[rr][cc]);
    unpack16(v0, v1, &vs[rr][cc]);
    __syncthreads();
    for (int n = 0; n < 64; ++n) {
      float4 k4 = *reinterpret_cast<const float4*>(&ks[n][ty * 4]);
      float4 v4 = *reinterpret_cast<const float4*>(&vs[n][tx * 4]);
      float ka[4] = {k4.x, k4.y, k4.z, k4.w};
      float va[4] = {v4.x, v4.y, v4.z, v4.w};
#pragma unroll
      for (int i = 0; i < 4; ++i)
#pragma unroll
        for (int j = 0; j < 4; ++j) acc[i][j] += ka[i] * va[j];
    }
  }
  float* dst = KV + (size_t)bh * 4096;
#pragma unroll
  for (int i = 0; i < 4; ++i)
#pragma unroll
    for (int j = 0; j < 4; ++j)
      atomicAdd(&dst[(ty * 4 + i) * 64 + tx * 4 + j], acc[i][j]);
}

// ---------- W2[b][j][h*64+d] = scale * sum_e KV[b,h,d,e] * Wo[j,h*64+e] ----------
__global__ __launch_bounds__(256) void w2_kernel(const float* __restrict__ KV,
                                                 const u16* __restrict__ wob,
                                                 u16* __restrict__ w2) {
  int bh = blockIdx.x & 31, jt = blockIdx.x >> 5;  // jt 0..7
  int b = bh >> 3, h = bh & 7;
  __shared__ float kvs[64][64];
  int t = threadIdx.x;
  {
    const float4* src = reinterpret_cast<const float4*>(KV + (size_t)bh * 4096);
    float4* dst = reinterpret_cast<float4*>(&kvs[0][0]);
#pragma unroll
    for (int i = 0; i < 4; ++i) dst[t + 256 * i] = src[t + 256 * i];
  }
  __syncthreads();
  int jloc = t & 127, dg = t >> 7;
  int j = jt * 128 + jloc;
  float wo[64];
  const u16* wr = wob + (size_t)j * 512 + h * 64;
#pragma unroll
  for (int e8 = 0; e8 < 8; ++e8) {
    uint4 pk = *reinterpret_cast<const uint4*>(wr + e8 * 8);
    u32 wds[4] = {pk.x, pk.y, pk.z, pk.w};
#pragma unroll
    for (int i = 0; i < 4; ++i) {
      wo[e8 * 8 + 2 * i]     = bf2f((u16)(wds[i] & 0xffffu));
      wo[e8 * 8 + 2 * i + 1] = bf2f((u16)(wds[i] >> 16));
    }
  }
  const float scale = 1.0f / 32768.0f;  // 1/(sqrt(64)*4096)
  u16* outp = w2 + ((size_t)b * 1024 + j) * 512 + h * 64 + dg * 32;
#pragma unroll
  for (int dd = 0; dd < 32; ++dd) {
    int d = dg * 32 + dd;
    float acc = 0.f;
    const float4* kr = reinterpret_cast<const float4*>(&kvs[d][0]);
#pragma unroll
    for (int e4 = 0; e4 < 16; ++e4) {
      float4 kv4 = kr[e4];
      acc += kv4.x * wo[e4 * 4] + kv4.y * wo[e4 * 4 + 1] +
             kv4.z * wo[e4 * 4 + 2] + kv4.w * wo[e4 * 4 + 3];
    }
    outp[dd] = f2b(acc * scale);
  }
}

// ---------- launch ----------
extern "C" void kernel_launch(void* const* d_in, const int* in_sizes, int n_in,
                              void* d_out, int out_size, void* d_ws, size_t ws_size,
                              hipStream_t stream) {
  const float* x  = (const float*)d_in[0];
  const float* Wq = (const float*)d_in[1];
  const float* gq = (const float*)d_in[2];
  const float* bq = (const float*)d_in[3];
  const float* gk = (const float*)d_in[4];
  const float* bk = (const float*)d_in[5];
  const float* Wo = (const float*)d_in[6];
  const float* bo = (const float*)d_in[7];
  float* out = (float*)d_out;

  char* p = (char*)d_ws;
  auto carve = [&](size_t bytes) {
    char* r = p;
    p += (bytes + 255) & ~(size_t)255;
    return r;
  };
  u16* wqb   = (u16*)carve((size_t)1536 * 1024 * 2);
  u16* wob   = (u16*)carve((size_t)1024 * 512 * 2);
  u16* qkv   = (u16*)carve((size_t)16384 * 1536 * 2);
  float* KVb = (float*)carve((size_t)32 * 64 * 64 * 4);
  u16* w2b   = (u16*)carve((size_t)4 * 1024 * 512 * 2);

  hipMemsetAsync(KVb, 0, (size_t)32 * 64 * 64 * 4, stream);
  cvt_bf16<<<1536, 256, 0, stream>>>(Wq, wqb, 393216);
  cvt_bf16<<<512, 256, 0, stream>>>(Wo, wob, 131072);
  // qkv = x @ Wqkv^T  [16384,1536]; A = fp32 x (in-kernel cvt), fused LN
  gemm_bt<0, 1><<<128 * 12, 256, 0, stream>>>(x, wqb, qkv, gq, bq, gk, bk,
                                              nullptr, 16384, 1536, 1024, 12,
                                              1024, 0);
  // KV = k^T v per (b,h)
  kv_accum<<<512, 256, 0, stream>>>(qkv, KVb);
  // W2[b] = scale * KV[b] @ Wo-slices
  w2_kernel<<<256, 256, 0, stream>>>(KVb, wob, w2b);
  // out = q @ W2[b]^T + b_out  [16384,1024] fp32  (A = q section of qkv)
  gemm_bt<1, 0><<<128 * 8, 256, 0, stream>>>(qkv, w2b, out, nullptr, nullptr,
                                             nullptr, nullptr, bo, 16384, 1024,
                                             512, 8, 1536, (size_t)1024 * 512);
}